// Round 3
// baseline (257.403 us; speedup 1.0000x reference)
//
#include <hip/hip_runtime.h>
#include <math.h>

namespace {
constexpr int kB  = 64;
constexpr int kT  = 1024;
constexpr int kK  = 512;
constexpr int kC  = 16;          // chunks over T (one wave per chunk)
constexpr int kL  = kT / kC;     // 64 steps per chunk, held in registers
constexpr int kKB = 64;          // k-values per block (= lanes per wave)
constexpr float kDT = 0.001f;
}

// Register-resident chunked linear scan. Block = (batch b, 64-k group),
// 1024 threads = 16 waves; wave c owns time chunk c. Each thread loads its
// 64 chunk inputs into registers ONCE (64 independent loads -> deep MLP),
// scans from zero state for the chunk-final state, combines true entry
// states through LDS (A^64 via 6 exact 2x2 squarings + <=15-step lookback),
// then re-scans from registers and writes. Global traffic is the ideal
// 134 MB read + 134 MB write (round-2's second read, 97 us, is eliminated).
// __launch_bounds__(1024,4) caps VGPR at 128 so the 16-wave block is resident.
__global__ __launch_bounds__(kKB * kC, 4) void alpha_scan3(
    const float* __restrict__ in,
    const float* __restrict__ init_level,
    const float* __restrict__ tau,
    float* __restrict__ out)
{
    __shared__ float sF0[kC][kKB];
    __shared__ float sF1[kC][kKB];

    const int lane = threadIdx.x & 63;      // k within group
    const int c    = threadIdx.x >> 6;      // chunk index (wave-uniform)
    const int kg   = blockIdx.x & 7;        // k group: 512/64 = 8
    const int b    = blockIdx.x >> 3;       // batch
    const int k    = kg * kKB + lane;

    // Per-feature coefficients (same arithmetic as reference).
    const float tc      = fmaxf(tau[k], 1e-8f);
    const float dt_tau  = kDT / tc;
    const float dt_tau2 = dt_tau / tc;
    const float e       = expf(-dt_tau);

    const float a00 = e * (1.0f - dt_tau);
    const float a01 = e * (-dt_tau2);
    const float a10 = e * kDT;
    const float a11 = e * (1.0f + dt_tau);
    const float b0  = e * dt_tau2;
    const float b1  = 1.0f - e * (1.0f + dt_tau);

    const float* __restrict__ pin =
        in + ((size_t)b * kT + (size_t)c * kL) * kK + k;

    // ---- Load the whole chunk into registers (64 independent loads) ----
    float u[kL];
    #pragma unroll
    for (int t = 0; t < kL; ++t) u[t] = pin[(size_t)t * kK];

    // ---- Phase A: local scan from zero state; final state only ----
    float x0 = 0.0f, x1 = 0.0f;
    #pragma unroll
    for (int t = 0; t < kL; ++t) {
        const float n0 = fmaf(a00, x0, fmaf(a01, x1, b0 * u[t]));
        const float n1 = fmaf(a10, x0, fmaf(a11, x1, b1 * u[t]));
        x0 = n0; x1 = n1;
    }
    sF0[c][lane] = x0;
    sF1[c][lane] = x1;
    __syncthreads();

    // ---- A^L = A^64 via 6 squarings (exact 2x2) ----
    float m00 = a00, m01 = a01, m10 = a10, m11 = a11;
    #pragma unroll
    for (int s = 0; s < 6; ++s) {
        const float t00 = fmaf(m00, m00, m01 * m10);
        const float t01 = fmaf(m00, m01, m01 * m11);
        const float t10 = fmaf(m10, m00, m11 * m10);
        const float t11 = fmaf(m10, m01, m11 * m11);
        m00 = t00; m01 = t01; m10 = t10; m11 = t11;
    }

    // ---- Combine: true entry state S_c for this chunk ----
    float s0 = 0.0f, s1 = init_level[k];
    for (int cp = 0; cp < c; ++cp) {          // wave-uniform trip count
        const float f0 = sF0[cp][lane];
        const float f1 = sF1[cp][lane];
        const float n0 = fmaf(m00, s0, fmaf(m01, s1, f0));
        const float n1 = fmaf(m10, s0, fmaf(m11, s1, f1));
        s0 = n0; s1 = n1;
    }

    // ---- Phase B: true scan from registers, write outputs ----
    x0 = s0; x1 = s1;
    float* __restrict__ pout =
        out + ((size_t)b * kT + (size_t)c * kL) * kK + k;
    #pragma unroll
    for (int t = 0; t < kL; ++t) {
        const float n0 = fmaf(a00, x0, fmaf(a01, x1, b0 * u[t]));
        const float n1 = fmaf(a10, x0, fmaf(a11, x1, b1 * u[t]));
        x0 = n0; x1 = n1;
        pout[(size_t)t * kK] = n1;
    }
}

extern "C" void kernel_launch(void* const* d_in, const int* in_sizes, int n_in,
                              void* d_out, int out_size, void* d_ws, size_t ws_size,
                              hipStream_t stream) {
    const float* in  = (const float*)d_in[0];   // [64,1024,512] fp32
    const float* il  = (const float*)d_in[1];   // [512] fp32
    const float* tau = (const float*)d_in[2];   // [512] fp32
    float* out = (float*)d_out;                 // [64,1024,512] fp32

    dim3 block(kKB * kC);                       // 1024 threads = 16 waves
    dim3 grid(kB * (kK / kKB));                 // 64 b x 8 k-groups = 512 blocks
    alpha_scan3<<<grid, block, 0, stream>>>(in, il, tau, out);
}

// Round 4
// 243.132 us; speedup vs baseline: 1.0587x; 1.0587x over previous
//
#include <hip/hip_runtime.h>
#include <math.h>

namespace {
constexpr int kB  = 64;
constexpr int kT  = 1024;
constexpr int kK  = 512;
constexpr int kC  = 32;          // chunks over T
constexpr int kL  = kT / kC;     // 32 steps per chunk, held in REGISTERS
constexpr int kKB = 32;          // k-values per block
constexpr float kDT = 0.001f;
}

// Register-resident chunked linear scan, round 4.
// Round-3 post-mortem: u[64] spilled to scratch (VGPR_Count=64, WRITE_SIZE
// +57 MB) and serialized the loads. Fix: u[32] (~70 VGPR total, fits the
// 128-VGPR cap from __launch_bounds__(1024,4) -> no spill).
// Block = 32 k-lanes x 32 chunks = 1024 threads; grid = 64 b x 16 k-groups.
// Each thread: 32 independent global loads into registers (8 KB in flight
// per wave; 16 waves/CU -> latency fully covered), local scan from zero,
// LDS combine (A^32 = 5 exact 2x2 squarings, <=31-step lookback), then
// re-scan from registers + coalesced stores. Traffic = ideal 134+134 MB.
__global__ __launch_bounds__(kKB * kC, 4) void alpha_scan4(
    const float* __restrict__ in,
    const float* __restrict__ init_level,
    const float* __restrict__ tau,
    float* __restrict__ out)
{
    __shared__ float sF0[kC][kKB];
    __shared__ float sF1[kC][kKB];

    const int lane = threadIdx.x & (kKB - 1);   // k within group (0..31)
    const int c    = threadIdx.x >> 5;          // chunk index (0..31)
    const int kg   = blockIdx.x & 15;           // k group: 512/32 = 16
    const int b    = blockIdx.x >> 4;           // batch
    const int k    = kg * kKB + lane;

    // Per-feature coefficients (same arithmetic as reference).
    const float tc      = fmaxf(tau[k], 1e-8f);
    const float dt_tau  = kDT / tc;
    const float dt_tau2 = dt_tau / tc;
    const float e       = expf(-dt_tau);

    const float a00 = e * (1.0f - dt_tau);
    const float a01 = e * (-dt_tau2);
    const float a10 = e * kDT;
    const float a11 = e * (1.0f + dt_tau);
    const float b0  = e * dt_tau2;
    const float b1  = 1.0f - e * (1.0f + dt_tau);

    const float* __restrict__ pin =
        in + ((size_t)b * kT + (size_t)c * kL) * kK + k;

    // ---- Load the whole chunk into registers (32 independent loads) ----
    float u[kL];
    #pragma unroll
    for (int t = 0; t < kL; ++t) u[t] = pin[(size_t)t * kK];

    // ---- Phase A: local scan from zero state; final state only ----
    float x0 = 0.0f, x1 = 0.0f;
    #pragma unroll
    for (int t = 0; t < kL; ++t) {
        const float n0 = fmaf(a00, x0, fmaf(a01, x1, b0 * u[t]));
        const float n1 = fmaf(a10, x0, fmaf(a11, x1, b1 * u[t]));
        x0 = n0; x1 = n1;
    }
    sF0[c][lane] = x0;
    sF1[c][lane] = x1;
    __syncthreads();

    // ---- A^L = A^32 via 5 squarings (exact 2x2) ----
    float m00 = a00, m01 = a01, m10 = a10, m11 = a11;
    #pragma unroll
    for (int s = 0; s < 5; ++s) {
        const float t00 = fmaf(m00, m00, m01 * m10);
        const float t01 = fmaf(m00, m01, m01 * m11);
        const float t10 = fmaf(m10, m00, m11 * m10);
        const float t11 = fmaf(m10, m01, m11 * m11);
        m00 = t00; m01 = t01; m10 = t10; m11 = t11;
    }

    // ---- Combine: true entry state S_c for this chunk ----
    float s0 = 0.0f, s1 = init_level[k];
    for (int cp = 0; cp < c; ++cp) {            // <=31 iterations
        const float f0 = sF0[cp][lane];
        const float f1 = sF1[cp][lane];
        const float n0 = fmaf(m00, s0, fmaf(m01, s1, f0));
        const float n1 = fmaf(m10, s0, fmaf(m11, s1, f1));
        s0 = n0; s1 = n1;
    }

    // ---- Phase B: true scan from registers, write outputs ----
    x0 = s0; x1 = s1;
    float* __restrict__ pout =
        out + ((size_t)b * kT + (size_t)c * kL) * kK + k;
    #pragma unroll
    for (int t = 0; t < kL; ++t) {
        const float n0 = fmaf(a00, x0, fmaf(a01, x1, b0 * u[t]));
        const float n1 = fmaf(a10, x0, fmaf(a11, x1, b1 * u[t]));
        x0 = n0; x1 = n1;
        pout[(size_t)t * kK] = n1;
    }
}

extern "C" void kernel_launch(void* const* d_in, const int* in_sizes, int n_in,
                              void* d_out, int out_size, void* d_ws, size_t ws_size,
                              hipStream_t stream) {
    const float* in  = (const float*)d_in[0];   // [64,1024,512] fp32
    const float* il  = (const float*)d_in[1];   // [512] fp32
    const float* tau = (const float*)d_in[2];   // [512] fp32
    float* out = (float*)d_out;                 // [64,1024,512] fp32

    dim3 block(kKB * kC);                       // 1024 threads = 16 waves
    dim3 grid(kB * (kK / kKB));                 // 64 b x 16 k-groups = 1024 blocks
    alpha_scan4<<<grid, block, 0, stream>>>(in, il, tau, out);
}